// Round 3
// baseline (863.172 us; speedup 1.0000x reference)
//
#include <hip/hip_runtime.h>
#include <hip/hip_bf16.h>

#define NROWS 131072
#define DDIM  256
#define CDIM  1024

#define L2E 1.4426950408889634f
#define LN2 0.6931471805599453f

typedef short bf16x8 __attribute__((ext_vector_type(8)));
typedef float f32x4 __attribute__((ext_vector_type(4)));

__device__ __forceinline__ unsigned short f2b(float x) {
    unsigned int u = __builtin_bit_cast(unsigned int, x);
    u = (u + 0x7FFFu + ((u >> 16) & 1u)) >> 16;   // round-to-nearest-even
    return (unsigned short)u;
}

// ---------------- 1) segment sums via global atomics ----------------
__global__ void k_segsum(const float* __restrict__ emb, const int* __restrict__ labels,
                         float* __restrict__ sums, float* __restrict__ counts) {
    const int t = threadIdx.x;
    const int sub = t >> 6;     // 4 rows per block-iteration
    const int lane = t & 63;
    for (int row = blockIdx.x * 4 + sub; row < NROWS; row += gridDim.x * 4) {
        const int lab = labels[row];
        const float4 v = *reinterpret_cast<const float4*>(emb + (size_t)row * DDIM + lane * 4);
        float* dst = sums + (size_t)lab * DDIM + lane * 4;
        atomicAdd(dst + 0, v.x);
        atomicAdd(dst + 1, v.y);
        atomicAdd(dst + 2, v.z);
        atomicAdd(dst + 3, v.w);
        if (lane == 0) atomicAdd(counts + lab, 1.0f);
    }
}

// ---------------- 2) centroids -> bf16 ----------------
__global__ void k_centroid(const float* __restrict__ sums, const float* __restrict__ counts,
                           unsigned short* __restrict__ cent) {
    const int c = blockIdx.x;
    const int t = threadIdx.x;   // 256 threads = 256 dims
    const float inv = 1.0f / counts[c];
    cent[c * DDIM + t] = f2b(sums[c * DDIM + t] * inv);
}

// ---------------- 3) fused GEMM + online softmax + NLL ----------------
// block = 256 thr (4 waves), BM = 64 rows, loop 16 chunks of 64 centroid cols.
// LDS: A[64][256] bf16 + B[64][256] bf16, both XOR-swizzled (byte ^= (row&7)<<4).
__launch_bounds__(256, 2)
__global__ void k_logits(const float* __restrict__ emb, const int* __restrict__ labels,
                         const unsigned short* __restrict__ cent, const float* __restrict__ wp,
                         float* __restrict__ nll_accum) {
    __shared__ unsigned short A_lds[64 * 256];
    __shared__ unsigned short B_lds[64 * 256];
    char* const Ab = reinterpret_cast<char*>(A_lds);
    char* const Bb = reinterpret_cast<char*>(B_lds);

    const float wscale = wp[0];
    const int t = threadIdx.x;
    const int wave = t >> 6;
    const int lane = t & 63;
    const int lg = lane >> 4;    // lane group 0..3
    const int lr = lane & 15;    // lane within group
    const int rowbase = blockIdx.x * 64;

    // ---- stage A: 64 rows x 256 dims fp32 -> bf16 LDS (coalesced float4) ----
    for (int i = 0; i < 16; ++i) {
        const int flat = i * 1024 + t * 4;
        const int row = flat >> 8;
        const int k = flat & 255;
        const float4 v = *reinterpret_cast<const float4*>(emb + (size_t)(rowbase + row) * DDIM + k);
        ushort4 h;
        h.x = f2b(v.x); h.y = f2b(v.y); h.z = f2b(v.z); h.w = f2b(v.w);
        const int byte = ((row << 9) + (k << 1)) ^ ((row & 7) << 4);
        *reinterpret_cast<ushort4*>(Ab + byte) = h;
    }
    __syncthreads();

    // ---- A fragments: per wave 16 rows, all K, kept in registers ----
    // A[m][k]: m = lane&15, k = (lane>>4)*8 + j  (consistent with B staging)
    bf16x8 af[8];
    {
        const int row = wave * 16 + lr;
#pragma unroll
        for (int kk = 0; kk < 8; ++kk) {
            const int byte = ((row << 9) + kk * 64 + lg * 16) ^ ((row & 7) << 4);
            af[kk] = *reinterpret_cast<const bf16x8*>(Ab + byte);
        }
    }

    // ---- per-lane online softmax state; C/D rows = (lane>>4)*4 + r ----
    float m[4], s[4], lv[4];
    int labs[4];
#pragma unroll
    for (int r = 0; r < 4; ++r) {
        m[r] = -1e30f; s[r] = 0.0f; lv[r] = 0.0f;
        labs[r] = labels[rowbase + wave * 16 + lg * 4 + r];
    }

    for (int cc = 0; cc < 16; ++cc) {
        __syncthreads();   // previous chunk fully consumed
        // ---- stage B chunk: 64 cols x 256 dims bf16 (coalesced 16B) ----
        const unsigned short* src = cent + cc * (64 * 256);
        for (int i = 0; i < 8; ++i) {
            const int flat = i * 2048 + t * 8;   // halfword index; col = flat>>8
            const int col = flat >> 8;
            const int k = flat & 255;
            const uint4 v = *reinterpret_cast<const uint4*>(src + flat);
            const int byte = ((col << 9) + (k << 1)) ^ ((col & 7) << 4);
            *reinterpret_cast<uint4*>(Bb + byte) = v;
        }
        __syncthreads();

#pragma unroll
        for (int ct = 0; ct < 4; ++ct) {
            f32x4 acc = {0.0f, 0.0f, 0.0f, 0.0f};
            const int brow = ct * 16 + lr;
#pragma unroll
            for (int kk = 0; kk < 8; ++kk) {
                const int byte = ((brow << 9) + kk * 64 + lg * 16) ^ ((brow & 7) << 4);
                const bf16x8 bf = *reinterpret_cast<const bf16x8*>(Bb + byte);
                acc = __builtin_amdgcn_mfma_f32_16x16x32_bf16(af[kk], bf, acc, 0, 0, 0);
            }
            const int colg = cc * 64 + ct * 16 + lr;
#pragma unroll
            for (int r = 0; r < 4; ++r) {
                const float v = wscale * acc[r];           // b cancels in lse - v_label
                const float mo = m[r];
                const float mn = fmaxf(mo, v);
                s[r] = s[r] * exp2f((mo - mn) * L2E) + exp2f((v - mn) * L2E);
                m[r] = mn;
                if (colg == labs[r]) lv[r] = v;
            }
        }
    }

    // ---- merge the 16 lanes of each row group, then accumulate NLL ----
    float part = 0.0f;
#pragma unroll
    for (int r = 0; r < 4; ++r) {
        float mm = m[r], ss = s[r], ll = lv[r];
#pragma unroll
        for (int off = 1; off < 16; off <<= 1) {
            const float mo = __shfl_xor(mm, off, 64);
            const float so = __shfl_xor(ss, off, 64);
            const float lo = __shfl_xor(ll, off, 64);
            const float mn = fmaxf(mm, mo);
            ss = ss * exp2f((mm - mn) * L2E) + so * exp2f((mo - mn) * L2E);
            mm = mn;
            ll += lo;   // exactly one lane holds the label logit, others 0
        }
        if (lr == 0) {
            const float lse = mm + log2f(ss) * LN2;
            part += (lse - ll);
        }
    }
    if (lr == 0) atomicAdd(nll_accum, part * (1.0f / NROWS));
}

// ---------------- 4) emit scalar ----------------
__global__ void k_final(const float* __restrict__ accum, float* __restrict__ out) {
    out[0] = accum[0];
}

extern "C" void kernel_launch(void* const* d_in, const int* in_sizes, int n_in,
                              void* d_out, int out_size, void* d_ws, size_t ws_size,
                              hipStream_t stream) {
    const float* emb = (const float*)d_in[0];
    const int* labels = (const int*)d_in[1];
    const float* wp = (const float*)d_in[2];
    // d_in[3] (b) cancels in the NLL; unused.
    float* out = (float*)d_out;

    // ws layout: sums (1 MB) | counts (4 KB) | accum (16 B pad) | centroids bf16 (512 KB)
    float* sums = (float*)d_ws;
    float* counts = sums + (size_t)CDIM * DDIM;            // +262144 floats
    float* accum = counts + CDIM;                          // +1024 floats
    unsigned short* cent = (unsigned short*)((char*)d_ws + 1052688);

    hipMemsetAsync(d_ws, 0, 1052688, stream);              // zero sums+counts+accum

    k_segsum<<<2048, 256, 0, stream>>>(emb, labels, sums, counts);
    k_centroid<<<CDIM, 256, 0, stream>>>(sums, counts, cent);
    k_logits<<<NROWS / 64, 256, 0, stream>>>(emb, labels, cent, wp, accum);
    k_final<<<1, 1, 0, stream>>>(accum, out);
}

// Round 5
// 488.122 us; speedup vs baseline: 1.7684x; 1.7684x over previous
//
#include <hip/hip_runtime.h>
#include <hip/hip_bf16.h>

#define NROWS 131072
#define DDIM  256
#define CDIM  1024

#define L2E 1.4426950408889634f
#define LN2 0.6931471805599453f

typedef short bf16x8 __attribute__((ext_vector_type(8)));
typedef float f32x4 __attribute__((ext_vector_type(4)));

__device__ __forceinline__ unsigned short f2b(float x) {
    unsigned int u = __builtin_bit_cast(unsigned int, x);
    u = (u + 0x7FFFu + ((u >> 16) & 1u)) >> 16;   // round-to-nearest-even
    return (unsigned short)u;
}

// ---------------- 1a) label histogram (131K int atomics, ~1000x fewer than fp32 segsum) ----
__global__ void k_hist(const int* __restrict__ labels, int* __restrict__ hist) {
    const int i = blockIdx.x * 256 + threadIdx.x;
    atomicAdd(&hist[labels[i]], 1);
}

// ---------------- 1b) exclusive prefix sum over 1024 counts ----------------
__global__ void k_scan(const int* __restrict__ hist, int* __restrict__ offsets) {
    __shared__ int tmp[CDIM];
    const int t = threadIdx.x;
    const int v = hist[t];
    tmp[t] = v;
    __syncthreads();
    for (int d = 1; d < CDIM; d <<= 1) {
        const int add = (t >= d) ? tmp[t - d] : 0;
        __syncthreads();
        tmp[t] += add;
        __syncthreads();
    }
    offsets[t] = tmp[t] - v;              // exclusive scan
    if (t == CDIM - 1) offsets[CDIM] = tmp[t];
}

// ---------------- 1c) scatter row indices into label-grouped order ----------------
__global__ void k_scatter(const int* __restrict__ labels, const int* __restrict__ offsets,
                          int* __restrict__ cursor, int* __restrict__ rowidx) {
    const int i = blockIdx.x * 256 + threadIdx.x;
    const int lab = labels[i];
    const int pos = atomicAdd(&cursor[lab], 1);
    rowidx[offsets[lab] + pos] = i;
}

// ---------------- 2) centroid gather: 1 block per label, atomic-free fp32 sum ----
__global__ void k_centroid(const float* __restrict__ emb, const int* __restrict__ rowidx,
                           const int* __restrict__ offsets, unsigned short* __restrict__ cent) {
    __shared__ f32x4 red[4][64];
    const int c = blockIdx.x;
    const int t = threadIdx.x;
    const int w = t >> 6;
    const int lane = t & 63;
    const int beg = offsets[c], end = offsets[c + 1];

    f32x4 acc = {0.0f, 0.0f, 0.0f, 0.0f};
    // 2 rows per wave-iteration for 2 loads in flight (latency overlap)
    for (int i = beg + w * 2; i < end; i += 8) {
        const int row0 = rowidx[i];
        const int row1 = (i + 1 < end) ? rowidx[i + 1] : -1;
        const float4 v0 = *reinterpret_cast<const float4*>(emb + (size_t)row0 * DDIM + lane * 4);
        if (row1 >= 0) {
            const float4 v1 = *reinterpret_cast<const float4*>(emb + (size_t)row1 * DDIM + lane * 4);
            acc[0] += v1.x; acc[1] += v1.y; acc[2] += v1.z; acc[3] += v1.w;
        }
        acc[0] += v0.x; acc[1] += v0.y; acc[2] += v0.z; acc[3] += v0.w;
    }
    red[w][lane] = acc;
    __syncthreads();
    if (t < 64) {
        const f32x4 a0 = red[0][t], a1 = red[1][t], a2 = red[2][t], a3 = red[3][t];
        const float inv = 1.0f / (float)(end - beg);
        ushort4 h;
        h.x = f2b((a0[0] + a1[0] + a2[0] + a3[0]) * inv);
        h.y = f2b((a0[1] + a1[1] + a2[1] + a3[1]) * inv);
        h.z = f2b((a0[2] + a1[2] + a2[2] + a3[2]) * inv);
        h.w = f2b((a0[3] + a1[3] + a2[3] + a3[3]) * inv);
        *reinterpret_cast<ushort4*>(cent + c * DDIM + t * 4) = h;
    }
}

// ---------------- 3) fused GEMM + online softmax + NLL ----------------
// block = 256 thr (4 waves), BM = 64 rows, loop 16 chunks of 64 centroid cols.
// LDS: A[64][256] bf16 + B[64][256] bf16, both XOR-swizzled (byte ^= (row&7)<<4).
__launch_bounds__(256, 2)
__global__ void k_logits(const float* __restrict__ emb, const int* __restrict__ labels,
                         const unsigned short* __restrict__ cent, const float* __restrict__ wp,
                         float* __restrict__ nll_accum) {
    __shared__ unsigned short A_lds[64 * 256];
    __shared__ unsigned short B_lds[64 * 256];
    char* const Ab = reinterpret_cast<char*>(A_lds);
    char* const Bb = reinterpret_cast<char*>(B_lds);

    const float wscale = wp[0];
    const int t = threadIdx.x;
    const int wave = t >> 6;
    const int lane = t & 63;
    const int lg = lane >> 4;    // lane group 0..3
    const int lr = lane & 15;    // lane within group
    const int rowbase = blockIdx.x * 64;

    // ---- stage A: 64 rows x 256 dims fp32 -> bf16 LDS (coalesced float4) ----
    for (int i = 0; i < 16; ++i) {
        const int flat = i * 1024 + t * 4;
        const int row = flat >> 8;
        const int k = flat & 255;
        const float4 v = *reinterpret_cast<const float4*>(emb + (size_t)(rowbase + row) * DDIM + k);
        ushort4 h;
        h.x = f2b(v.x); h.y = f2b(v.y); h.z = f2b(v.z); h.w = f2b(v.w);
        const int byte = ((row << 9) + (k << 1)) ^ ((row & 7) << 4);
        *reinterpret_cast<ushort4*>(Ab + byte) = h;
    }
    __syncthreads();

    // ---- A fragments: per wave 16 rows, all K, kept in registers ----
    // A[m][k]: m = lane&15, k = (lane>>4)*8 + j  (consistent with B staging)
    bf16x8 af[8];
    {
        const int row = wave * 16 + lr;
#pragma unroll
        for (int kk = 0; kk < 8; ++kk) {
            const int byte = ((row << 9) + kk * 64 + lg * 16) ^ ((row & 7) << 4);
            af[kk] = *reinterpret_cast<const bf16x8*>(Ab + byte);
        }
    }

    // ---- per-lane online softmax state; C/D rows = (lane>>4)*4 + r ----
    float m[4], s[4], lv[4];
    int labs[4];
#pragma unroll
    for (int r = 0; r < 4; ++r) {
        m[r] = -1e30f; s[r] = 0.0f; lv[r] = 0.0f;
        labs[r] = labels[rowbase + wave * 16 + lg * 4 + r];
    }

    for (int cc = 0; cc < 16; ++cc) {
        __syncthreads();   // previous chunk fully consumed
        // ---- stage B chunk: 64 cols x 256 dims bf16 (coalesced 16B) ----
        const unsigned short* src = cent + cc * (64 * 256);
        for (int i = 0; i < 8; ++i) {
            const int flat = i * 2048 + t * 8;   // halfword index; col = flat>>8
            const int col = flat >> 8;
            const int k = flat & 255;
            const uint4 v = *reinterpret_cast<const uint4*>(src + flat);
            const int byte = ((col << 9) + (k << 1)) ^ ((col & 7) << 4);
            *reinterpret_cast<uint4*>(Bb + byte) = v;
        }
        __syncthreads();

        float vals[4][4];
#pragma unroll
        for (int ct = 0; ct < 4; ++ct) {
            f32x4 acc = {0.0f, 0.0f, 0.0f, 0.0f};
            const int brow = ct * 16 + lr;
#pragma unroll
            for (int kk = 0; kk < 8; ++kk) {
                const int byte = ((brow << 9) + kk * 64 + lg * 16) ^ ((brow & 7) << 4);
                const bf16x8 bf = *reinterpret_cast<const bf16x8*>(Bb + byte);
                acc = __builtin_amdgcn_mfma_f32_16x16x32_bf16(af[kk], bf, acc, 0, 0, 0);
            }
            const int colg = cc * 64 + ct * 16 + lr;
#pragma unroll
            for (int r = 0; r < 4; ++r) {
                const float v = wscale * acc[r];           // b cancels in lse - v_label
                vals[ct][r] = v;
                if (colg == labs[r]) lv[r] = v;
            }
        }
        // ---- batched online-softmax update: 5 exp2 per row per chunk (was 8) ----
#pragma unroll
        for (int r = 0; r < 4; ++r) {
            const float cmax = fmaxf(fmaxf(vals[0][r], vals[1][r]),
                                     fmaxf(vals[2][r], vals[3][r]));
            const float mo = m[r];
            const float mn = fmaxf(mo, cmax);
            const float ssum = exp2f((vals[0][r] - mn) * L2E) + exp2f((vals[1][r] - mn) * L2E)
                             + exp2f((vals[2][r] - mn) * L2E) + exp2f((vals[3][r] - mn) * L2E);
            s[r] = s[r] * exp2f((mo - mn) * L2E) + ssum;
            m[r] = mn;
        }
    }

    // ---- merge the 16 lanes of each row group, then accumulate NLL ----
    float part = 0.0f;
#pragma unroll
    for (int r = 0; r < 4; ++r) {
        float mm = m[r], ss = s[r], ll = lv[r];
#pragma unroll
        for (int off = 1; off < 16; off <<= 1) {
            const float mo = __shfl_xor(mm, off, 64);
            const float so = __shfl_xor(ss, off, 64);
            const float lo = __shfl_xor(ll, off, 64);
            const float mn = fmaxf(mm, mo);
            ss = ss * exp2f((mm - mn) * L2E) + so * exp2f((mo - mn) * L2E);
            mm = mn;
            ll += lo;   // exactly one lane holds the label logit, others 0
        }
        if (lr == 0) {
            const float lse = mm + log2f(ss) * LN2;
            part += (lse - ll);
        }
    }
    if (lr == 0) atomicAdd(nll_accum, part * (1.0f / NROWS));
}

// ---------------- 4) emit scalar ----------------
__global__ void k_final(const float* __restrict__ accum, float* __restrict__ out) {
    out[0] = accum[0];
}

extern "C" void kernel_launch(void* const* d_in, const int* in_sizes, int n_in,
                              void* d_out, int out_size, void* d_ws, size_t ws_size,
                              hipStream_t stream) {
    const float* emb = (const float*)d_in[0];
    const int* labels = (const int*)d_in[1];
    const float* wp = (const float*)d_in[2];
    // d_in[3] (b) cancels in the NLL; unused.
    float* out = (float*)d_out;

    // ws byte layout:
    //   0       hist     int[1024]    (4 KB)
    //   4096    cursor   int[1024]    (4 KB)
    //   8192    offsets  int[1025]
    //   12544   accum    float
    //   16384   rowidx   int[131072]  (512 KB)
    //   540672  cent     u16[262144]  (512 KB)   -> total 1.02 MB (< prior 1.58 MB use)
    int* hist = (int*)d_ws;
    int* cursor = (int*)((char*)d_ws + 4096);
    int* offsets = (int*)((char*)d_ws + 8192);
    float* accum = (float*)((char*)d_ws + 12544);
    int* rowidx = (int*)((char*)d_ws + 16384);
    unsigned short* cent = (unsigned short*)((char*)d_ws + 540672);

    hipMemsetAsync(d_ws, 0, 16384, stream);   // zero hist + cursor + offsets + accum

    k_hist<<<NROWS / 256, 256, 0, stream>>>(labels, hist);
    k_scan<<<1, CDIM, 0, stream>>>(hist, offsets);
    k_scatter<<<NROWS / 256, 256, 0, stream>>>(labels, offsets, cursor, rowidx);
    k_centroid<<<CDIM, 256, 0, stream>>>(emb, rowidx, offsets, cent);
    k_logits<<<NROWS / 64, 256, 0, stream>>>(emb, labels, cent, wp, accum);
    k_final<<<1, 1, 0, stream>>>(accum, out);
}

// Round 6
// 456.482 us; speedup vs baseline: 1.8909x; 1.0693x over previous
//
#include <hip/hip_runtime.h>
#include <hip/hip_bf16.h>

#define NROWS 131072
#define DDIM  256
#define CDIM  1024

#define L2E 1.4426950408889634f
#define LN2 0.6931471805599453f

typedef short bf16x8 __attribute__((ext_vector_type(8)));
typedef float f32x4 __attribute__((ext_vector_type(4)));

#define GLOAD_LDS16(g, l) __builtin_amdgcn_global_load_lds( \
    (const __attribute__((address_space(1))) void*)(g),      \
    (__attribute__((address_space(3))) void*)(l), 16, 0, 0)

__device__ __forceinline__ unsigned short f2b(float x) {
    unsigned int u = __builtin_bit_cast(unsigned int, x);
    u = (u + 0x7FFFu + ((u >> 16) & 1u)) >> 16;   // round-to-nearest-even
    return (unsigned short)u;
}

// ---------------- 1) fused hist + scan + scatter (1 block, 1024 thr) --------
// Also zeroes d_out (stream-ordered before k_logits accumulation).
__global__ void k_prep(const int* __restrict__ labels, int* __restrict__ offsets,
                       int* __restrict__ rowidx, float* __restrict__ out) {
    __shared__ int h[CDIM];
    __shared__ int c[CDIM];
    const int t = threadIdx.x;
    h[t] = 0;
    __syncthreads();
    const int4* l4 = (const int4*)labels;
    for (int i = t; i < NROWS / 4; i += 1024) {
        const int4 v = l4[i];
        atomicAdd(&h[v.x], 1); atomicAdd(&h[v.y], 1);
        atomicAdd(&h[v.z], 1); atomicAdd(&h[v.w], 1);
    }
    __syncthreads();
    // inclusive scan in c
    const int v = h[t];
    c[t] = v;
    __syncthreads();
    for (int d = 1; d < CDIM; d <<= 1) {
        const int add = (t >= d) ? c[t - d] : 0;
        __syncthreads();
        c[t] += add;
        __syncthreads();
    }
    const int excl = c[t] - v;
    offsets[t] = excl;
    if (t == CDIM - 1) offsets[CDIM] = c[t];
    c[t] = excl;                       // cursor = exclusive offset
    if (t == 0) out[0] = 0.0f;         // zero the output accumulator
    __syncthreads();
    for (int i = t; i < NROWS / 4; i += 1024) {
        const int4 v4 = l4[i];
        const int base = i * 4;
        int p;
        p = atomicAdd(&c[v4.x], 1); rowidx[p] = base;
        p = atomicAdd(&c[v4.y], 1); rowidx[p] = base + 1;
        p = atomicAdd(&c[v4.z], 1); rowidx[p] = base + 2;
        p = atomicAdd(&c[v4.w], 1); rowidx[p] = base + 3;
    }
}

// ---------------- 2) centroid gather -> bf16 in MFMA-granule order ----------
// centG granule (cc,ct,kk,lane=(lg*16+lr)): 16B = cent[col=cc*64+ct*16+lr][k=kk*32+lg*8 ..+8]
// halfword index = cc*16384 + ct*4096 + kk*512 + (lg*16+lr)*8
__global__ void k_centroid(const float* __restrict__ emb, const int* __restrict__ rowidx,
                           const int* __restrict__ offsets, unsigned short* __restrict__ centG) {
    __shared__ f32x4 red[4][64];
    const int cgrp = blockIdx.x;
    const int t = threadIdx.x;
    const int w = t >> 6;
    const int lane = t & 63;
    const int beg = offsets[cgrp], end = offsets[cgrp + 1];

    f32x4 acc = {0.0f, 0.0f, 0.0f, 0.0f};
    for (int i = beg + w * 2; i < end; i += 8) {
        const int row0 = rowidx[i];
        const int row1 = (i + 1 < end) ? rowidx[i + 1] : -1;
        const float4 v0 = *reinterpret_cast<const float4*>(emb + (size_t)row0 * DDIM + lane * 4);
        if (row1 >= 0) {
            const float4 v1 = *reinterpret_cast<const float4*>(emb + (size_t)row1 * DDIM + lane * 4);
            acc[0] += v1.x; acc[1] += v1.y; acc[2] += v1.z; acc[3] += v1.w;
        }
        acc[0] += v0.x; acc[1] += v0.y; acc[2] += v0.z; acc[3] += v0.w;
    }
    red[w][lane] = acc;
    __syncthreads();
    if (t < 32) {
        const float inv = 1.0f / (float)(end - beg);
        f32x4 a = red[0][2 * t], b4 = red[0][2 * t + 1];
#pragma unroll
        for (int ww = 1; ww < 4; ++ww) {
            const f32x4 x = red[ww][2 * t], y = red[ww][2 * t + 1];
            a[0] += x[0]; a[1] += x[1]; a[2] += x[2]; a[3] += x[3];
            b4[0] += y[0]; b4[1] += y[1]; b4[2] += y[2]; b4[3] += y[3];
        }
        uint4 u;
        u.x = (unsigned)f2b(a[0] * inv) | ((unsigned)f2b(a[1] * inv) << 16);
        u.y = (unsigned)f2b(a[2] * inv) | ((unsigned)f2b(a[3] * inv) << 16);
        u.z = (unsigned)f2b(b4[0] * inv) | ((unsigned)f2b(b4[1] * inv) << 16);
        u.w = (unsigned)f2b(b4[2] * inv) | ((unsigned)f2b(b4[3] * inv) << 16);
        const int cc = cgrp >> 6, ctq = (cgrp >> 4) & 3, lr2 = cgrp & 15;
        const int kk = t >> 2, lg2 = t & 3;
        *reinterpret_cast<uint4*>(centG + (size_t)cc * 16384 + ctq * 4096 + kk * 512
                                  + (lg2 * 16 + lr2) * 8) = u;
    }
}

// ---------------- 3) fused GEMM + online softmax + NLL ----------------
// 4 waves, BM=64. B via global_load_lds DMA into fragment-order LDS (double-buffered,
// buf0 doubles as the A staging buffer). One barrier per 64-col chunk; DMA issued
// before compute so L2 latency hides under MFMA+softmax.
__launch_bounds__(256, 2)
__global__ void k_logits(const float* __restrict__ emb, const int* __restrict__ labels,
                         const unsigned short* __restrict__ centG, const float* __restrict__ wp,
                         float* __restrict__ out) {
    __shared__ unsigned short lds[2][16384];   // 2 x 32 KB
    char* const Ab = reinterpret_cast<char*>(&lds[0][0]);

    const float wscale = wp[0];
    const int t = threadIdx.x;
    const int w = t >> 6;
    const int lane = t & 63;
    const int lg = lane >> 4;
    const int lr = lane & 15;
    const int rowbase = blockIdx.x * 64;

    // ---- issue B chunk-0 DMA -> lds[1] (8 x 1KB contiguous per wave) ----
#pragma unroll
    for (int j = 0; j < 8; ++j) {
        const int J = w * 8 + j;
        GLOAD_LDS16(centG + J * 512 + lane * 8, &lds[1][J * 512]);
    }

    // ---- stage A: 64 rows x 256 dims fp32 -> bf16, XOR-swizzled, into lds[0] ----
    for (int i = 0; i < 16; ++i) {
        const int flat = i * 1024 + t * 4;
        const int row = flat >> 8;
        const int k = flat & 255;
        const float4 v = *reinterpret_cast<const float4*>(emb + (size_t)(rowbase + row) * DDIM + k);
        ushort4 hh;
        hh.x = f2b(v.x); hh.y = f2b(v.y); hh.z = f2b(v.z); hh.w = f2b(v.w);
        const int byte = ((row << 9) + (k << 1)) ^ ((row & 7) << 4);
        *reinterpret_cast<ushort4*>(Ab + byte) = hh;
    }
    __syncthreads();   // drains A ds_writes AND B0 DMA (vmcnt+lgkm before barrier)

    // ---- A fragments to registers: A[m=lr][k=kk*32+lg*8+j] ----
    bf16x8 af[8];
    {
        const int row = w * 16 + lr;
#pragma unroll
        for (int kk = 0; kk < 8; ++kk) {
            const int byte = ((row << 9) + kk * 64 + lg * 16) ^ ((row & 7) << 4);
            af[kk] = *reinterpret_cast<const bf16x8*>(Ab + byte);
        }
    }
    __syncthreads();   // all waves done reading A before buf0 becomes a B buffer

    float m[4], s[4], lv[4];
    int labs[4];
#pragma unroll
    for (int r = 0; r < 4; ++r) {
        m[r] = -1e30f; s[r] = 0.0f; lv[r] = 0.0f;
        labs[r] = labels[rowbase + w * 16 + lg * 4 + r];
    }

    for (int cc = 0; cc < 16; ++cc) {
        // ---- issue next-chunk DMA before compute (latency hides under MFMA) ----
        if (cc < 15) {
            const unsigned short* src = centG + (cc + 1) * 16384;
#pragma unroll
            for (int j = 0; j < 8; ++j) {
                const int J = w * 8 + j;
                GLOAD_LDS16(src + J * 512 + lane * 8, &lds[cc & 1][J * 512]);
            }
        }
        // ---- compute current chunk from lds[(cc+1)&1]; lane-linear reads ----
        const unsigned short* bb = &lds[(cc + 1) & 1][lane * 8];
        float vals[4][4];
#pragma unroll
        for (int ct = 0; ct < 4; ++ct) {
            f32x4 acc = {0.0f, 0.0f, 0.0f, 0.0f};
#pragma unroll
            for (int kk = 0; kk < 8; ++kk) {
                const bf16x8 bf = *reinterpret_cast<const bf16x8*>(bb + ct * 4096 + kk * 512);
                acc = __builtin_amdgcn_mfma_f32_16x16x32_bf16(af[kk], bf, acc, 0, 0, 0);
            }
            const int colg = cc * 64 + ct * 16 + lr;
#pragma unroll
            for (int r = 0; r < 4; ++r) {
                const float v = wscale * acc[r];           // b cancels in lse - v_label
                vals[ct][r] = v;
                if (colg == labs[r]) lv[r] = v;
            }
        }
        // ---- batched online-softmax update (5 exp2 per row per chunk) ----
#pragma unroll
        for (int r = 0; r < 4; ++r) {
            const float cmax = fmaxf(fmaxf(vals[0][r], vals[1][r]),
                                     fmaxf(vals[2][r], vals[3][r]));
            const float mo = m[r];
            const float mn = fmaxf(mo, cmax);
            const float ssum = exp2f((vals[0][r] - mn) * L2E) + exp2f((vals[1][r] - mn) * L2E)
                             + exp2f((vals[2][r] - mn) * L2E) + exp2f((vals[3][r] - mn) * L2E);
            s[r] = s[r] * exp2f((mo - mn) * L2E) + ssum;
            m[r] = mn;
        }
        __syncthreads();   // next buffer staged + all reads of current done
    }

    // ---- merge the 16 lanes of each row group, accumulate NLL into d_out ----
    float part = 0.0f;
#pragma unroll
    for (int r = 0; r < 4; ++r) {
        float mm = m[r], ss = s[r], ll = lv[r];
#pragma unroll
        for (int off = 1; off < 16; off <<= 1) {
            const float mo = __shfl_xor(mm, off, 64);
            const float so = __shfl_xor(ss, off, 64);
            const float lo = __shfl_xor(ll, off, 64);
            const float mn = fmaxf(mm, mo);
            ss = ss * exp2f((mm - mn) * L2E) + so * exp2f((mo - mn) * L2E);
            mm = mn;
            ll += lo;
        }
        if (lr == 0) {
            const float lse = mm + log2f(ss) * LN2;
            part += (lse - ll);
        }
    }
    if (lr == 0) atomicAdd(out, part * (1.0f / NROWS));
}

extern "C" void kernel_launch(void* const* d_in, const int* in_sizes, int n_in,
                              void* d_out, int out_size, void* d_ws, size_t ws_size,
                              hipStream_t stream) {
    const float* emb = (const float*)d_in[0];
    const int* labels = (const int*)d_in[1];
    const float* wp = (const float*)d_in[2];
    // d_in[3] (b) cancels in the NLL; unused.
    float* out = (float*)d_out;

    // ws byte layout:
    //   0       offsets  int[1025]
    //   8192    rowidx   int[131072]   (512 KB)
    //   532480  centG    u16[262144]   (512 KB, granule order)  -> 1.03 MB total
    int* offsets = (int*)d_ws;
    int* rowidx = (int*)((char*)d_ws + 8192);
    unsigned short* centG = (unsigned short*)((char*)d_ws + 532480);

    k_prep<<<1, 1024, 0, stream>>>(labels, offsets, rowidx, out);
    k_centroid<<<CDIM, 256, 0, stream>>>(emb, rowidx, offsets, centG);
    k_logits<<<NROWS / 64, 256, 0, stream>>>(emb, labels, centG, wp, out);
}

// Round 11
// 423.288 us; speedup vs baseline: 2.0392x; 1.0784x over previous
//
#include <hip/hip_runtime.h>
#include <hip/hip_bf16.h>

#define NROWS 131072
#define DDIM  256
#define CDIM  1024

#define L2E 1.4426950408889634f
#define LN2 0.6931471805599453f

typedef short bf16x8 __attribute__((ext_vector_type(8)));
typedef float f32x4 __attribute__((ext_vector_type(4)));

#define GLOAD_LDS16(g, l) __builtin_amdgcn_global_load_lds( \
    (const __attribute__((address_space(1))) void*)(g),      \
    (__attribute__((address_space(3))) void*)(l), 16, 0, 0)

__device__ __forceinline__ unsigned short f2b(float x) {
    unsigned int u = __builtin_bit_cast(unsigned int, x);
    u = (u + 0x7FFFu + ((u >> 16) & 1u)) >> 16;   // round-to-nearest-even
    return (unsigned short)u;
}

// ---------------- 1a) label histogram: grid-parallel global atomics ---------
__global__ void k_hist(const int* __restrict__ labels, int* __restrict__ hist) {
    const int i = blockIdx.x * 256 + threadIdx.x;
    atomicAdd(&hist[labels[i]], 1);
}

// ---------------- 1b) exclusive scan over 1024 counts; zero out accumulator -
__global__ void k_scan(const int* __restrict__ hist, int* __restrict__ offsets,
                       float* __restrict__ out) {
    __shared__ int tmp[CDIM];
    const int t = threadIdx.x;
    const int v = hist[t];
    tmp[t] = v;
    __syncthreads();
    for (int d = 1; d < CDIM; d <<= 1) {
        const int add = (t >= d) ? tmp[t - d] : 0;
        __syncthreads();
        tmp[t] += add;
        __syncthreads();
    }
    offsets[t] = tmp[t] - v;
    if (t == CDIM - 1) offsets[CDIM] = tmp[t];
    if (t == 0) out[0] = 0.0f;
}

// ---------------- 1c) scatter row indices into label-grouped order ----------
__global__ void k_scatter(const int* __restrict__ labels, const int* __restrict__ offsets,
                          int* __restrict__ cursor, int* __restrict__ rowidx) {
    const int i = blockIdx.x * 256 + threadIdx.x;
    const int lab = labels[i];
    const int pos = atomicAdd(&cursor[lab], 1);
    rowidx[offsets[lab] + pos] = i;
}

// ---------------- 2) centroid gather -> bf16 in MFMA-granule order ----------
// granule (cc,ct,kk,lane): 16B = cent[col=cc*64+ct*16+lr][k=kk*32+lg*8 ..+8]
// halfword index = cc*16384 + ct*4096 + kk*512 + lane*8
__global__ void k_centroid(const float* __restrict__ emb, const int* __restrict__ rowidx,
                           const int* __restrict__ offsets, unsigned short* __restrict__ centG) {
    __shared__ int ridx[256];
    __shared__ f32x4 red[4][64];
    const int cgrp = blockIdx.x;
    const int t = threadIdx.x;
    const int w = t >> 6;
    const int lane = t & 63;
    const int beg = offsets[cgrp], end = offsets[cgrp + 1];

    f32x4 acc = {0.0f, 0.0f, 0.0f, 0.0f};
    for (int base = beg; base < end; base += 256) {
        const int cnt = min(256, end - base);
        __syncthreads();
        if (t < cnt) ridx[t] = rowidx[base + t];
        __syncthreads();
        // 4 rows in flight per wave (VMEM ILP=4)
        for (int i = w * 4; i < cnt; i += 16) {
            float4 v[4];
            int nr = min(4, cnt - i);
#pragma unroll
            for (int j = 0; j < 4; ++j) {
                if (j < nr) {
                    const int row = ridx[i + j];
                    v[j] = *reinterpret_cast<const float4*>(emb + (size_t)row * DDIM + lane * 4);
                } else {
                    v[j] = make_float4(0.f, 0.f, 0.f, 0.f);
                }
            }
#pragma unroll
            for (int j = 0; j < 4; ++j) {
                acc[0] += v[j].x; acc[1] += v[j].y; acc[2] += v[j].z; acc[3] += v[j].w;
            }
        }
    }
    red[w][lane] = acc;
    __syncthreads();
    if (t < 32) {
        const float inv = 1.0f / (float)(end - beg);
        f32x4 a = red[0][2 * t], b4 = red[0][2 * t + 1];
#pragma unroll
        for (int ww = 1; ww < 4; ++ww) {
            const f32x4 x = red[ww][2 * t], y = red[ww][2 * t + 1];
            a[0] += x[0]; a[1] += x[1]; a[2] += x[2]; a[3] += x[3];
            b4[0] += y[0]; b4[1] += y[1]; b4[2] += y[2]; b4[3] += y[3];
        }
        uint4 u;
        u.x = (unsigned)f2b(a[0] * inv) | ((unsigned)f2b(a[1] * inv) << 16);
        u.y = (unsigned)f2b(a[2] * inv) | ((unsigned)f2b(a[3] * inv) << 16);
        u.z = (unsigned)f2b(b4[0] * inv) | ((unsigned)f2b(b4[1] * inv) << 16);
        u.w = (unsigned)f2b(b4[2] * inv) | ((unsigned)f2b(b4[3] * inv) << 16);
        const int cc = cgrp >> 6, ctq = (cgrp >> 4) & 3, lr2 = cgrp & 15;
        const int kk = t >> 2, lg2 = t & 3;
        *reinterpret_cast<uint4*>(centG + (size_t)cc * 16384 + ctq * 4096 + kk * 512
                                  + (lg2 * 16 + lr2) * 8) = u;
    }
}

// ---------------- 3) fused GEMM + online softmax + NLL ----------------
// BM=128, 512 thr (8 waves, wave owns 16 rows). A direct to registers (no A-LDS).
// LDS = B double-buffer only (2 x 32KB) -> 2 blocks/CU = 16 waves/CU.
// Counted-drain barriers: own-wave vmcnt(0) + raw s_barrier (no full __syncthreads drain).
__launch_bounds__(512, 4)
__global__ void k_logits(const float* __restrict__ emb, const int* __restrict__ labels,
                         const unsigned short* __restrict__ centG, const float* __restrict__ wp,
                         float* __restrict__ out) {
    __shared__ unsigned short lds[2][16384];   // 2 x 32 KB

    const float wl2e = wp[0] * L2E;            // fold w and 1/ln2 into one scale
    const int t = threadIdx.x;
    const int w = t >> 6;                      // 0..7
    const int lane = t & 63;
    const int lg = lane >> 4;
    const int lr = lane & 15;
    const int rowbase = blockIdx.x * 128;
    const int myrow = rowbase + w * 16 + lr;

    // ---- issue B chunk-0 DMA -> lds[1]: 8 waves x 4 x 1KB ----
#pragma unroll
    for (int j = 0; j < 4; ++j) {
        const int J = w * 4 + j;
        GLOAD_LDS16(centG + J * 512 + lane * 8, &lds[1][J * 512]);
    }
    __builtin_amdgcn_sched_barrier(0);

    // ---- A fragments direct from global (L3-warm): A[m=lr][k=kk*32+lg*8+j] ----
    bf16x8 af[8];
#pragma unroll
    for (int kk = 0; kk < 8; ++kk) {
        const float* src = emb + (size_t)myrow * DDIM + kk * 32 + lg * 8;
        const float4 a0 = *reinterpret_cast<const float4*>(src);
        const float4 a1 = *reinterpret_cast<const float4*>(src + 4);
        bf16x8 f;
        f[0] = (short)f2b(a0.x); f[1] = (short)f2b(a0.y);
        f[2] = (short)f2b(a0.z); f[3] = (short)f2b(a0.w);
        f[4] = (short)f2b(a1.x); f[5] = (short)f2b(a1.y);
        f[6] = (short)f2b(a1.z); f[7] = (short)f2b(a1.w);
        af[kk] = f;
    }

    // ---- per-lane online state in log2 domain; C/D rows = lg*4 + r ----
    float m[4], s[4], lv[4];
    int labs[4];
#pragma unroll
    for (int r = 0; r < 4; ++r) {
        m[r] = -1e30f; s[r] = 0.0f; lv[r] = 0.0f;
        labs[r] = labels[rowbase + w * 16 + lg * 4 + r];
    }

    // wait own DMA + A loads, then cross-wave barrier
    asm volatile("s_waitcnt vmcnt(0)" ::: "memory");
    __builtin_amdgcn_s_barrier();

    for (int cc = 0; cc < 16; ++cc) {
        if (cc < 15) {
            const unsigned short* src = centG + (cc + 1) * 16384;
#pragma unroll
            for (int j = 0; j < 4; ++j) {
                const int J = w * 4 + j;
                GLOAD_LDS16(src + J * 512 + lane * 8, &lds[cc & 1][J * 512]);
            }
            __builtin_amdgcn_sched_barrier(0);
        }
        const unsigned short* bb = &lds[(cc + 1) & 1][lane * 8];
        float vals[4][4];
#pragma unroll
        for (int ct = 0; ct < 4; ++ct) {
            f32x4 acc = {0.0f, 0.0f, 0.0f, 0.0f};
#pragma unroll
            for (int kk = 0; kk < 8; ++kk) {
                const bf16x8 bf = *reinterpret_cast<const bf16x8*>(bb + ct * 4096 + kk * 512);
                acc = __builtin_amdgcn_mfma_f32_16x16x32_bf16(af[kk], bf, acc, 0, 0, 0);
            }
            const int colg = cc * 64 + ct * 16 + lr;
#pragma unroll
            for (int r = 0; r < 4; ++r) {
                const float e = wl2e * acc[r];            // log2-domain logit
                vals[ct][r] = e;
                if (colg == labs[r]) lv[r] = e;
            }
        }
#pragma unroll
        for (int r = 0; r < 4; ++r) {
            const float cmax = fmaxf(fmaxf(fmaxf(vals[0][r], vals[1][r]), vals[2][r]),
                                     vals[3][r]);         // nests -> v_max3
            const float mo = m[r];
            const float mn = fmaxf(mo, cmax);
            const float ssum = exp2f(vals[0][r] - mn) + exp2f(vals[1][r] - mn)
                             + exp2f(vals[2][r] - mn) + exp2f(vals[3][r] - mn);
            s[r] = s[r] * exp2f(mo - mn) + ssum;          // exp2(0)=1 when mn==mo
            m[r] = mn;
        }
        asm volatile("s_waitcnt vmcnt(0)" ::: "memory");  // own DMA for cc+1 landed
        __builtin_amdgcn_s_barrier();                     // all waves done reading
    }

    // ---- merge 16 lanes per row group; accumulate NLL (log2 units -> *LN2) ----
    float part = 0.0f;
#pragma unroll
    for (int r = 0; r < 4; ++r) {
        float mm = m[r], ss = s[r], ll = lv[r];
#pragma unroll
        for (int off = 1; off < 16; off <<= 1) {
            const float mo = __shfl_xor(mm, off, 64);
            const float so = __shfl_xor(ss, off, 64);
            const float lo = __shfl_xor(ll, off, 64);
            const float mn = fmaxf(mm, mo);
            ss = ss * exp2f(mm - mn) + so * exp2f(mo - mn);
            mm = mn;
            ll += lo;
        }
        if (lr == 0) part += (mm + log2f(ss) - ll);
    }
    if (lr == 0) atomicAdd(out, part * (LN2 / NROWS));
}

extern "C" void kernel_launch(void* const* d_in, const int* in_sizes, int n_in,
                              void* d_out, int out_size, void* d_ws, size_t ws_size,
                              hipStream_t stream) {
    const float* emb = (const float*)d_in[0];
    const int* labels = (const int*)d_in[1];
    const float* wp = (const float*)d_in[2];
    // d_in[3] (b) cancels in the NLL; unused.
    float* out = (float*)d_out;

    // ws byte layout:
    //   0       hist     int[1024]   (4 KB)
    //   4096    cursor   int[1024]   (4 KB)
    //   8192    offsets  int[1025]
    //   16384   rowidx   int[131072] (512 KB)
    //   540672  centG    u16[262144] (512 KB, granule order)
    int* hist = (int*)d_ws;
    int* cursor = (int*)((char*)d_ws + 4096);
    int* offsets = (int*)((char*)d_ws + 8192);
    int* rowidx = (int*)((char*)d_ws + 16384);
    unsigned short* centG = (unsigned short*)((char*)d_ws + 540672);

    hipMemsetAsync(d_ws, 0, 8192, stream);    // zero hist + cursor

    k_hist<<<NROWS / 256, 256, 0, stream>>>(labels, hist);
    k_scan<<<1, CDIM, 0, stream>>>(hist, offsets, out);
    k_scatter<<<NROWS / 256, 256, 0, stream>>>(labels, offsets, cursor, rowidx);
    k_centroid<<<CDIM, 256, 0, stream>>>(emb, rowidx, offsets, centG);
    k_logits<<<NROWS / 128, 512, 0, stream>>>(emb, labels, centG, wp, out);
}